// Round 6
// baseline (331.316 us; speedup 1.0000x reference)
//
#include <hip/hip_runtime.h>
#include <stdint.h>

typedef __attribute__((ext_vector_type(8))) short s16x8;
typedef __attribute__((ext_vector_type(8))) _Float16 h16x8;
typedef __attribute__((ext_vector_type(4))) float f32x4;

__device__ __forceinline__ unsigned short f2h_bits(float f) {
  union { _Float16 h; unsigned short u; } cv;
  cv.h = (_Float16)f;
  return cv.u;
}
__device__ __forceinline__ f32x4 mfma16h(h16x8 a, h16x8 b, f32x4 c) {
  return __builtin_amdgcn_mfma_f32_16x16x32_f16(a, b, c, 0, 0, 0);
}

// Vt write: thread owns absolute e-rows (e, e+1) x t-range tg*8..tg*8+7.
// Layout: [256 e][64 t] f16, byte = e*128 + ((2t) ^ (((e>>1)&7)<<4)).
__device__ __forceinline__ void write_vq(char* base, int e, int tg, const float2* g) {
  s16x8 lo, hi;
#pragma unroll
  for (int j = 0; j < 8; ++j) {
    lo[j] = (short)f2h_bits(g[j].x);
    hi[j] = (short)f2h_bits(g[j].y);
  }
  int sw = ((e >> 1) & 7) << 4;
  *(s16x8*)(base + e * 128 + ((16 * tg) ^ sw)) = lo;
  *(s16x8*)(base + (e + 1) * 128 + ((16 * tg) ^ sw)) = hi;
}

// ---------------- attention kernel: one block per batch ----------------
// fp16 pipeline, ONE barrier total.
// LDS 40960 B: Vt [256 e][64 t] f16 swizzled @0 (32 KB), P [64][64] f16 @32768.
// V gathers issued before/between QK phases (ride QK's vmcnt waits);
// g2/g3 latency hidden under softmax; PV runs 4 quarters barrier-free.
__global__ __launch_bounds__(256) void attn_kernel(
    const float* __restrict__ Vg, const float* __restrict__ Kg,
    const float* __restrict__ Qg, float* __restrict__ attn_out,
    unsigned short* __restrict__ xb /* f16 x = attn+q, may be null */) {
  __shared__ __align__(16) char smem[40960];
  char* PLB = smem + 32768;

  const int b = blockIdx.x;
  const int tid = threadIdx.x;
  const int lane = tid & 63;
  const int w = tid >> 6;  // wave id: owns S/A rows 16w..16w+15
  const int n = lane & 15;
  const int q = lane >> 4;

  const float* Qb = Qg + (size_t)b * 64 * 256;
  const float* Kb = Kg + (size_t)b * 64 * 256;
  const float* Vb = Vg + (size_t)b * 64 * 256;

  const int ep2 = (tid & 31) * 2;  // e-pair within a 64-col quarter (0..62)
  const int tg = tid >> 5;         // 0..7: t = tg*8..tg*8+7

  f32x4 accS[4];
#pragma unroll
  for (int c = 0; c < 4; ++c) accS[c] = f32x4{0.f, 0.f, 0.f, 0.f};

  // V gathers, quarter 0 (retired for free by QK ph0's waits)
  float2 g0[8];
#pragma unroll
  for (int j = 0; j < 8; ++j) g0[j] = *(const float2*)(Vb + (tg * 8 + j) * 256 + 0 + ep2);

  // ---- S = Q K^T: fragments direct from global, fp16 ----
#pragma unroll
  for (int kk = 0; kk < 4; ++kk) {
    const int cb = kk * 32 + q * 8;
    const float* qsrc = Qb + (16 * w + n) * 256 + cb;
    float4 q0 = *(const float4*)qsrc;
    float4 q1 = *(const float4*)(qsrc + 4);
    float4 k0[4], k1[4];
#pragma unroll
    for (int c = 0; c < 4; ++c) {
      const float* ksrc = Kb + (16 * c + n) * 256 + cb;
      k0[c] = *(const float4*)ksrc;
      k1[c] = *(const float4*)(ksrc + 4);
    }
    h16x8 qh;
    qh[0] = (_Float16)q0.x; qh[1] = (_Float16)q0.y;
    qh[2] = (_Float16)q0.z; qh[3] = (_Float16)q0.w;
    qh[4] = (_Float16)q1.x; qh[5] = (_Float16)q1.y;
    qh[6] = (_Float16)q1.z; qh[7] = (_Float16)q1.w;
#pragma unroll
    for (int c = 0; c < 4; ++c) {
      h16x8 kh;
      kh[0] = (_Float16)k0[c].x; kh[1] = (_Float16)k0[c].y;
      kh[2] = (_Float16)k0[c].z; kh[3] = (_Float16)k0[c].w;
      kh[4] = (_Float16)k1[c].x; kh[5] = (_Float16)k1[c].y;
      kh[6] = (_Float16)k1[c].z; kh[7] = (_Float16)k1[c].w;
      accS[c] = mfma16h(qh, kh, accS[c]);
    }
  }

  // V gathers, quarter 1 (rides QK ph1's waits)
  float2 g1[8];
#pragma unroll
  for (int j = 0; j < 8; ++j) g1[j] = *(const float2*)(Vb + (tg * 8 + j) * 256 + 64 + ep2);

#pragma unroll
  for (int kk = 0; kk < 4; ++kk) {
    const int cb = kk * 32 + q * 8;
    const float* qsrc = Qb + (16 * w + n) * 256 + 128 + cb;
    float4 q0 = *(const float4*)qsrc;
    float4 q1 = *(const float4*)(qsrc + 4);
    float4 k0[4], k1[4];
#pragma unroll
    for (int c = 0; c < 4; ++c) {
      const float* ksrc = Kb + (16 * c + n) * 256 + 128 + cb;
      k0[c] = *(const float4*)ksrc;
      k1[c] = *(const float4*)(ksrc + 4);
    }
    h16x8 qh;
    qh[0] = (_Float16)q0.x; qh[1] = (_Float16)q0.y;
    qh[2] = (_Float16)q0.z; qh[3] = (_Float16)q0.w;
    qh[4] = (_Float16)q1.x; qh[5] = (_Float16)q1.y;
    qh[6] = (_Float16)q1.z; qh[7] = (_Float16)q1.w;
#pragma unroll
    for (int c = 0; c < 4; ++c) {
      h16x8 kh;
      kh[0] = (_Float16)k0[c].x; kh[1] = (_Float16)k0[c].y;
      kh[2] = (_Float16)k0[c].z; kh[3] = (_Float16)k0[c].w;
      kh[4] = (_Float16)k1[c].x; kh[5] = (_Float16)k1[c].y;
      kh[6] = (_Float16)k1[c].z; kh[7] = (_Float16)k1[c].w;
      accS[c] = mfma16h(qh, kh, accS[c]);
    }
  }

  // stage V quarters 0,1 (already retired); then issue quarters 2,3
  write_vq(smem, 0 + ep2, tg, g0);
  write_vq(smem, 64 + ep2, tg, g1);
  float2 g2[8], g3[8];
#pragma unroll
  for (int j = 0; j < 8; ++j) g2[j] = *(const float2*)(Vb + (tg * 8 + j) * 256 + 128 + ep2);
#pragma unroll
  for (int j = 0; j < 8; ++j) g3[j] = *(const float2*)(Vb + (tg * 8 + j) * 256 + 192 + ep2);

  // ---- in-register softmax (hides g2/g3 latency) ----
  const float scale = 0.125f;
  float p[4][4];
#pragma unroll
  for (int r = 0; r < 4; ++r) {
    float m = -1e30f;
#pragma unroll
    for (int c = 0; c < 4; ++c) m = fmaxf(m, accS[c][r]);
#pragma unroll
    for (int mk = 1; mk < 16; mk <<= 1) m = fmaxf(m, __shfl_xor(m, mk, 64));
    float s = 0.f;
#pragma unroll
    for (int c = 0; c < 4; ++c) {
      float e = __expf((accS[c][r] - m) * scale);
      p[c][r] = e;
      s += e;
    }
#pragma unroll
    for (int mk = 1; mk < 16; mk <<= 1) s += __shfl_xor(s, mk, 64);
    float inv = 1.0f / s;
#pragma unroll
    for (int c = 0; c < 4; ++c) p[c][r] *= inv;
  }

  write_vq(smem, 128 + ep2, tg, g2);
  write_vq(smem, 192 + ep2, tg, g3);

  // ---- P to LDS (f16; wave-local rows, no barrier needed for P) ----
#pragma unroll
  for (int r = 0; r < 4; ++r) {
    int row = 16 * w + 4 * q + r;
    int sw = (row & 7) << 4;
#pragma unroll
    for (int c = 0; c < 4; ++c)
      *(unsigned short*)(PLB + row * 128 + ((2 * (16 * c + n)) ^ sw)) =
          f2h_bits(p[c][r]);
  }

  __syncthreads();  // the ONLY barrier: Vt fully staged, nothing useful in flight

  // ---- A = P V, 4 e-quarters, barrier-free; epilogue streams per quarter ----
  f32x4 accA[4];
#pragma unroll
  for (int qi = 0; qi < 4; ++qi) {
#pragma unroll
    for (int c = 0; c < 4; ++c) accA[c] = f32x4{0.f, 0.f, 0.f, 0.f};
    __builtin_amdgcn_s_setprio(1);
#pragma unroll
    for (int ks = 0; ks < 2; ++ks) {
      const int cb = (ks * 32 + q * 8) * 2;
      h16x8 af = *(const h16x8*)(PLB + (16 * w + n) * 128 + (cb ^ ((n & 7) << 4)));
#pragma unroll
      for (int c = 0; c < 4; ++c) {
        int row = qi * 64 + 16 * c + n;
        h16x8 bf = *(const h16x8*)(smem + row * 128 + (cb ^ (((row >> 1) & 7) << 4)));
        accA[c] = mfma16h(af, bf, accA[c]);
      }
    }
    __builtin_amdgcn_s_setprio(0);

#pragma unroll
    for (int r = 0; r < 4; ++r) {
      int t = 16 * w + 4 * q + r;
      const float* qrow = Qb + t * 256 + qi * 64;
      size_t base = ((size_t)b * 64 + t) * 256 + qi * 64;
#pragma unroll
      for (int c = 0; c < 4; ++c) {
        int e = 16 * c + n;
        float aval = accA[c][r];
        attn_out[base + e] = aval;
        if (xb) xb[base + e] = f2h_bits(aval + qrow[e]);
      }
    }
  }
}

// ---------------- W_ff fp32 -> f16 ----------------
__global__ __launch_bounds__(256) void w2b_kernel(const float* __restrict__ W,
                                                  unsigned short* __restrict__ Wb) {
  int i = blockIdx.x * 256 + threadIdx.x;  // one float4 each, grid covers exactly
  float4 v = ((const float4*)W)[i];
  ushort4 o;
  o.x = f2h_bits(v.x); o.y = f2h_bits(v.y); o.z = f2h_bits(v.z); o.w = f2h_bits(v.w);
  ((ushort4*)Wb)[i] = o;
}

// ---------------- FF GEMM: out_part = x @ W^T, 64x64 tiles, K-split ----------------
// Pipelined double-buffer: 1 raw barrier per K-iter with lgkmcnt-only wait;
// tile t+2's global loads stay in flight across the barrier (no vmcnt drain).
template <bool USE_XB>
__global__ __launch_bounds__(256) void ff_kernel(
    const unsigned short* __restrict__ xb, const float* __restrict__ attn,
    const float* __restrict__ query, const unsigned short* __restrict__ Wb,
    float* __restrict__ part, int kchunk) {
  __shared__ __align__(16) unsigned short As[2][64 * 72];
  __shared__ __align__(16) unsigned short Bs[2][64 * 72];
  const int tid = threadIdx.x;
  const int lane = tid & 63, w = tid >> 6, n = lane & 15, q = lane >> 4;
  const int m0 = blockIdx.x * 64;
  const int n0 = blockIdx.y * 64;
  const int k0 = blockIdx.z * kchunk;

  f32x4 acc[4];
#pragma unroll
  for (int c = 0; c < 4; ++c) acc[c] = f32x4{0.f, 0.f, 0.f, 0.f};

  const int srow = tid >> 3;  // 0..31
  const int scol = (tid & 7) * 8;
  const int nIter = kchunk >> 6;

  uint4 ra[2], rb[2];      // USE_XB staging regs (tile in flight)
  float4 fa[2][2], fq[2][2];  // fp32-path staging

#define FF_LOAD(t)                                                   \
  {                                                                  \
    int kk = (t)*64;                                                 \
    _Pragma("unroll") for (int rr = 0; rr < 2; ++rr) {               \
      int row = rr * 32 + srow;                                      \
      size_t ga = (size_t)(m0 + row) * 16384 + k0 + kk + scol;       \
      if (USE_XB) {                                                  \
        ra[rr] = *(const uint4*)(xb + ga);                           \
      } else {                                                       \
        fa[rr][0] = *(const float4*)(attn + ga);                     \
        fa[rr][1] = *(const float4*)(attn + ga + 4);                 \
        fq[rr][0] = *(const float4*)(query + ga);                    \
        fq[rr][1] = *(const float4*)(query + ga + 4);                \
      }                                                              \
      size_t gw = (size_t)(n0 + row) * 16384 + k0 + kk + scol;       \
      rb[rr] = *(const uint4*)(Wb + gw);                             \
    }                                                                \
  }

#define FF_WRITE(bufi)                                               \
  {                                                                  \
    _Pragma("unroll") for (int rr = 0; rr < 2; ++rr) {               \
      int row = rr * 32 + srow;                                      \
      if (USE_XB) {                                                  \
        *(uint4*)(&As[bufi][row * 72 + scol]) = ra[rr];              \
      } else {                                                       \
        ushort4 h0, h1;                                              \
        h0.x = f2h_bits(fa[rr][0].x + fq[rr][0].x);                  \
        h0.y = f2h_bits(fa[rr][0].y + fq[rr][0].y);                  \
        h0.z = f2h_bits(fa[rr][0].z + fq[rr][0].z);                  \
        h0.w = f2h_bits(fa[rr][0].w + fq[rr][0].w);                  \
        h1.x = f2h_bits(fa[rr][1].x + fq[rr][1].x);                  \
        h1.y = f2h_bits(fa[rr][1].y + fq[rr][1].y);                  \
        h1.z = f2h_bits(fa[rr][1].z + fq[rr][1].z);                  \
        h1.w = f2h_bits(fa[rr][1].w + fq[rr][1].w);                  \
        *(ushort4*)(&As[bufi][row * 72 + scol]) = h0;                \
        *(ushort4*)(&As[bufi][row * 72 + scol + 4]) = h1;            \
      }                                                              \
      *(uint4*)(&Bs[bufi][row * 72 + scol]) = rb[rr];                \
    }                                                                \
  }

  FF_LOAD(0);
  FF_WRITE(0);
  FF_LOAD(1);
  asm volatile("s_waitcnt lgkmcnt(0)" ::: "memory");
  __builtin_amdgcn_s_barrier();

  for (int t = 0; t < nIter; ++t) {
    const int cur = t & 1;
#pragma unroll
    for (int ks = 0; ks < 2; ++ks) {
      const int colb = ks * 32 + q * 8;
      h16x8 af = *(const h16x8*)(&As[cur][(16 * w + n) * 72 + colb]);
#pragma unroll
      for (int c = 0; c < 4; ++c) {
        h16x8 bf = *(const h16x8*)(&Bs[cur][(16 * c + n) * 72 + colb]);
        acc[c] = mfma16h(af, bf, acc[c]);
      }
    }
    if (t + 1 < nIter) {
      FF_WRITE(cur ^ 1);  // tile t+1 (regs); waits vmcnt for them only
      if (t + 2 < nIter) FF_LOAD(t + 2);  // stays in flight across barrier
      asm volatile("s_waitcnt lgkmcnt(0)" ::: "memory");
      __builtin_amdgcn_s_barrier();
    }
  }
#undef FF_LOAD
#undef FF_WRITE

#pragma unroll
  for (int r = 0; r < 4; ++r) {
    int m = m0 + 16 * w + 4 * q + r;
#pragma unroll
    for (int c = 0; c < 4; ++c) {
      int nn = n0 + 16 * c + n;
      part[((size_t)blockIdx.z * 2048 + m) * 256 + nn] = acc[c][r];
    }
  }
}

// ---------------- reduce K-split partials + bias + ReLU ----------------
__global__ __launch_bounds__(256) void relu_kernel(const float* __restrict__ part,
                                                   const float* __restrict__ bias,
                                                   float* __restrict__ out, int KS) {
  int idx = blockIdx.x * 256 + threadIdx.x;
  float s = bias[idx & 255];
  for (int ks = 0; ks < KS; ++ks) s += part[(size_t)ks * 2048 * 256 + idx];
  out[idx] = fmaxf(s, 0.f);
}

extern "C" void kernel_launch(void* const* d_in, const int* in_sizes, int n_in,
                              void* d_out, int out_size, void* d_ws, size_t ws_size,
                              hipStream_t stream) {
  const float* value = (const float*)d_in[0];
  const float* key   = (const float*)d_in[1];
  const float* query = (const float*)d_in[2];
  // d_in[3] = mask, unused by the block
  const float* W_ff  = (const float*)d_in[4];
  const float* b_ff  = (const float*)d_in[5];

  float* out  = (float*)d_out;
  float* attn = out + (size_t)2048 * 256;  // outputs: (out, attention) concatenated

  const int KS = 4;
  const size_t wb_bytes   = (size_t)256 * 16384 * 2;      // 8 MB f16 W
  const size_t part_bytes = (size_t)KS * 2048 * 256 * 4;  // 8 MB fp32 partials
  const size_t xb_bytes   = (size_t)2048 * 64 * 256 * 2;  // 64 MB f16 x
  unsigned short* Wb = (unsigned short*)d_ws;
  float* part = (float*)((char*)d_ws + wb_bytes);
  bool use_xb = ws_size >= wb_bytes + part_bytes + xb_bytes;
  unsigned short* xb =
      use_xb ? (unsigned short*)((char*)d_ws + wb_bytes + part_bytes) : nullptr;

  w2b_kernel<<<4096, 256, 0, stream>>>(W_ff, Wb);
  attn_kernel<<<2048, 256, 0, stream>>>(value, key, query, attn, xb);
  dim3 gb(32, 4, KS);
  if (use_xb)
    ff_kernel<true><<<gb, 256, 0, stream>>>(xb, nullptr, nullptr, Wb, part, 16384 / KS);
  else
    ff_kernel<false><<<gb, 256, 0, stream>>>(nullptr, attn, query, Wb, part, 16384 / KS);
  relu_kernel<<<2048, 256, 0, stream>>>(part, b_ff, out, KS);
}

// Round 7
// 280.286 us; speedup vs baseline: 1.1821x; 1.1821x over previous
//
#include <hip/hip_runtime.h>
#include <stdint.h>

typedef __attribute__((ext_vector_type(8))) short s16x8;
typedef __attribute__((ext_vector_type(8))) _Float16 h16x8;
typedef __attribute__((ext_vector_type(4))) float f32x4;

__device__ __forceinline__ unsigned short f2h_bits(float f) {
  union { _Float16 h; unsigned short u; } cv;
  cv.h = (_Float16)f;
  return cv.u;
}
__device__ __forceinline__ f32x4 mfma16h(h16x8 a, h16x8 b, f32x4 c) {
  return __builtin_amdgcn_mfma_f32_16x16x32_f16(a, b, c, 0, 0, 0);
}

// async global->LDS, 16 B per lane. LDS dest = wave-uniform base + lane*16.
typedef const unsigned int __attribute__((address_space(1)))* as1_u32p;
typedef unsigned int __attribute__((address_space(3)))* as3_u32p;
__device__ __forceinline__ void async_ld16(const void* g, void* l) {
  __builtin_amdgcn_global_load_lds((as1_u32p)g, (as3_u32p)l, 16, 0, 0);
}

// Stage one 64-col fp32 K-quarter (16 KB) into buf, linear LDS layout
// buf[row*256 + c16*16] = K[row][qi*64 + (c16 ^ (row&7))*4 ..+3]  (source pre-swizzle).
// 4 instructions per wave, 1 KB each -> 4 KB in flight per wave, no VGPR dests.
__device__ __forceinline__ void stage_kq(char* buf, const float* Kb, int qi,
                                         int w, int lane) {
#pragma unroll
  for (int i = 0; i < 4; ++i) {
    int seg = w * 4 + i;            // 0..15, covers 4 rows each
    int row = seg * 4 + (lane >> 4);
    int sg = (lane & 15) ^ (row & 7);
    async_ld16(Kb + row * 256 + qi * 64 + sg * 4, buf + seg * 1024);
  }
}

// QK^T for one e-quarter: Q fragments direct global->reg, K fragments from the
// staged LDS quarter (swizzled granule read -> uniform bank spread).
__device__ __forceinline__ void qk_quarter(const char* buf, const float* Qb, int qi,
                                           int w, int n, int q, f32x4* accS) {
#pragma unroll
  for (int kkl = 0; kkl < 2; ++kkl) {
    const float* qsrc = Qb + (16 * w + n) * 256 + qi * 64 + kkl * 32 + q * 8;
    float4 q0 = *(const float4*)qsrc;
    float4 q1 = *(const float4*)(qsrc + 4);
    h16x8 qh;
    qh[0] = (_Float16)q0.x; qh[1] = (_Float16)q0.y;
    qh[2] = (_Float16)q0.z; qh[3] = (_Float16)q0.w;
    qh[4] = (_Float16)q1.x; qh[5] = (_Float16)q1.y;
    qh[6] = (_Float16)q1.z; qh[7] = (_Float16)q1.w;
    const int g = kkl * 8 + q * 2;
#pragma unroll
    for (int c = 0; c < 4; ++c) {
      int row = 16 * c + n;
      int s = row & 7;
      float4 k0 = *(const float4*)(buf + row * 256 + ((g ^ s) * 16));
      float4 k1 = *(const float4*)(buf + row * 256 + (((g + 1) ^ s) * 16));
      h16x8 kh;
      kh[0] = (_Float16)k0.x; kh[1] = (_Float16)k0.y;
      kh[2] = (_Float16)k0.z; kh[3] = (_Float16)k0.w;
      kh[4] = (_Float16)k1.x; kh[5] = (_Float16)k1.y;
      kh[6] = (_Float16)k1.z; kh[7] = (_Float16)k1.w;
      accS[c] = mfma16h(qh, kh, accS[c]);
    }
  }
}

// Vt write: thread owns absolute e-rows (e, e+1) x t-range tg*8..tg*8+7.
// Layout: [256 e][64 t] f16, byte = e*128 + ((2t) ^ (((e>>1)&7)<<4)).
__device__ __forceinline__ void write_vq(char* base, int e, int tg, const float2* g) {
  s16x8 lo, hi;
#pragma unroll
  for (int j = 0; j < 8; ++j) {
    lo[j] = (short)f2h_bits(g[j].x);
    hi[j] = (short)f2h_bits(g[j].y);
  }
  int sw = ((e >> 1) & 7) << 4;
  *(s16x8*)(base + e * 128 + ((16 * tg) ^ sw)) = lo;
  *(s16x8*)(base + (e + 1) * 128 + ((16 * tg) ^ sw)) = hi;
}

// ---------------- attention kernel: one block per batch ----------------
// K staged fp32 via global_load_lds (async DMA depth >> VGPR-bound loads):
//   b0 @0 (16 KB), b1 @16384 (16 KB) - double-buffered e-quarters
//   Vt @32768 (32 KB) f16 [256][64] swizzled
//   P  @0 (8 KB, overlays b0 after QK done)          total 65536 B
__global__ __launch_bounds__(256, 2) void attn_kernel(
    const float* __restrict__ Vg, const float* __restrict__ Kg,
    const float* __restrict__ Qg, float* __restrict__ attn_out,
    unsigned short* __restrict__ xb /* f16 x = attn+q, may be null */) {
  __shared__ __align__(16) char smem[65536];
  char* b0 = smem;
  char* b1 = smem + 16384;
  char* Vt = smem + 32768;
  char* PLB = smem;  // overlays b0 after its last read

  const int b = blockIdx.x;
  const int tid = threadIdx.x;
  const int lane = tid & 63;
  const int w = tid >> 6;  // wave id: owns S/A rows 16w..16w+15
  const int n = lane & 15;
  const int q = lane >> 4;

  const float* Qb = Qg + (size_t)b * 64 * 256;
  const float* Kb = Kg + (size_t)b * 64 * 256;
  const float* Vb = Vg + (size_t)b * 64 * 256;

  const int ep2 = (tid & 31) * 2;  // V staging: e-pair within a 64-col quarter
  const int tg = tid >> 5;         // 0..7: t = tg*8..tg*8+7

  f32x4 accS[4];
#pragma unroll
  for (int c = 0; c < 4; ++c) accS[c] = f32x4{0.f, 0.f, 0.f, 0.f};

  // ---- prologue: 32 KB of K async + V quarters 0,1 in flight, then one drain
  stage_kq(b0, Kb, 0, w, lane);
  stage_kq(b1, Kb, 1, w, lane);
  float2 g0[8], g1[8];
#pragma unroll
  for (int j = 0; j < 8; ++j) g0[j] = *(const float2*)(Vb + (tg * 8 + j) * 256 + 0 + ep2);
#pragma unroll
  for (int j = 0; j < 8; ++j) g1[j] = *(const float2*)(Vb + (tg * 8 + j) * 256 + 64 + ep2);
  __syncthreads();  // drain happens while 32KB+8KB/block is in flight (saturated)

  write_vq(Vt, 0 + ep2, tg, g0);
  write_vq(Vt, 64 + ep2, tg, g1);
  float2 g2[8], g3[8];
#pragma unroll
  for (int j = 0; j < 8; ++j) g2[j] = *(const float2*)(Vb + (tg * 8 + j) * 256 + 128 + ep2);
#pragma unroll
  for (int j = 0; j < 8; ++j) g3[j] = *(const float2*)(Vb + (tg * 8 + j) * 256 + 192 + ep2);

  qk_quarter(b0, Qb, 0, w, n, q, accS);
  __syncthreads();  // b0 free
  stage_kq(b0, Kb, 2, w, lane);        // in flight under q1 compute
  qk_quarter(b1, Qb, 1, w, n, q, accS);
  __syncthreads();  // b1 free; drains stage q2 + g2,g3
  stage_kq(b1, Kb, 3, w, lane);        // in flight under q2 compute
  write_vq(Vt, 128 + ep2, tg, g2);
  write_vq(Vt, 192 + ep2, tg, g3);
  qk_quarter(b0, Qb, 2, w, n, q, accS);
  __syncthreads();  // drains stage q3
  qk_quarter(b1, Qb, 3, w, n, q, accS);

  // ---- in-register softmax. lane holds S[16w+4q+r][16c+n] in accS[c][r] ----
  const float scale = 0.125f;
  float p[4][4];
#pragma unroll
  for (int r = 0; r < 4; ++r) {
    float m = -1e30f;
#pragma unroll
    for (int c = 0; c < 4; ++c) m = fmaxf(m, accS[c][r]);
#pragma unroll
    for (int mk = 1; mk < 16; mk <<= 1) m = fmaxf(m, __shfl_xor(m, mk, 64));
    float s = 0.f;
#pragma unroll
    for (int c = 0; c < 4; ++c) {
      float e = __expf((accS[c][r] - m) * scale);
      p[c][r] = e;
      s += e;
    }
#pragma unroll
    for (int mk = 1; mk < 16; mk <<= 1) s += __shfl_xor(s, mk, 64);
    float inv = 1.0f / s;
#pragma unroll
    for (int c = 0; c < 4; ++c) p[c][r] *= inv;
  }

  // ---- P to LDS (f16, overlays b0 - all b0 reads finished before last sync) ----
#pragma unroll
  for (int r = 0; r < 4; ++r) {
    int row = 16 * w + 4 * q + r;
    int sw = (row & 7) << 4;
#pragma unroll
    for (int c = 0; c < 4; ++c)
      *(unsigned short*)(PLB + row * 128 + ((2 * (16 * c + n)) ^ sw)) =
          f2h_bits(p[c][r]);
  }

  __syncthreads();  // Vt + P visible

  // ---- A = P V, 4 e-quarters, barrier-free; epilogue streams per quarter ----
  f32x4 accA[4];
#pragma unroll
  for (int qi = 0; qi < 4; ++qi) {
#pragma unroll
    for (int c = 0; c < 4; ++c) accA[c] = f32x4{0.f, 0.f, 0.f, 0.f};
    __builtin_amdgcn_s_setprio(1);
#pragma unroll
    for (int ks = 0; ks < 2; ++ks) {
      const int cb = (ks * 32 + q * 8) * 2;
      h16x8 af = *(const h16x8*)(PLB + (16 * w + n) * 128 + (cb ^ ((n & 7) << 4)));
#pragma unroll
      for (int c = 0; c < 4; ++c) {
        int row = qi * 64 + 16 * c + n;
        h16x8 bf = *(const h16x8*)(Vt + row * 128 + (cb ^ (((row >> 1) & 7) << 4)));
        accA[c] = mfma16h(af, bf, accA[c]);
      }
    }
    __builtin_amdgcn_s_setprio(0);

#pragma unroll
    for (int r = 0; r < 4; ++r) {
      int t = 16 * w + 4 * q + r;
      const float* qrow = Qb + t * 256 + qi * 64;
      size_t base = ((size_t)b * 64 + t) * 256 + qi * 64;
#pragma unroll
      for (int c = 0; c < 4; ++c) {
        int e = 16 * c + n;
        float aval = accA[c][r];
        attn_out[base + e] = aval;
        if (xb) xb[base + e] = f2h_bits(aval + qrow[e]);
      }
    }
  }
}

// ---------------- W_ff fp32 -> f16 ----------------
__global__ __launch_bounds__(256) void w2b_kernel(const float* __restrict__ W,
                                                  unsigned short* __restrict__ Wb) {
  int i = blockIdx.x * 256 + threadIdx.x;  // one float4 each, grid covers exactly
  float4 v = ((const float4*)W)[i];
  ushort4 o;
  o.x = f2h_bits(v.x); o.y = f2h_bits(v.y); o.z = f2h_bits(v.z); o.w = f2h_bits(v.w);
  ((ushort4*)Wb)[i] = o;
}

// ---------------- FF GEMM: out_part = x @ W^T, 64x64 tiles, K-split ----------------
// (round-5 version; the round-6 "pipelined" rewrite regressed ~45 us - reverted)
template <bool USE_XB>
__global__ __launch_bounds__(256) void ff_kernel(
    const unsigned short* __restrict__ xb, const float* __restrict__ attn,
    const float* __restrict__ query, const unsigned short* __restrict__ Wb,
    float* __restrict__ part, int kchunk) {
  __shared__ __align__(16) unsigned short As[64 * 72];
  __shared__ __align__(16) unsigned short Bs[64 * 72];
  const int tid = threadIdx.x;
  const int lane = tid & 63, w = tid >> 6, n = lane & 15, q = lane >> 4;
  const int m0 = blockIdx.x * 64;
  const int n0 = blockIdx.y * 64;
  const int k0 = blockIdx.z * kchunk;

  f32x4 acc[4];
#pragma unroll
  for (int c = 0; c < 4; ++c) acc[c] = f32x4{0.f, 0.f, 0.f, 0.f};

  const int srow = tid >> 3;  // 0..31
  const int scol = (tid & 7) * 8;

  for (int kk = 0; kk < kchunk; kk += 64) {
#pragma unroll
    for (int rr = 0; rr < 2; ++rr) {
      int row = rr * 32 + srow;
      size_t ga = (size_t)(m0 + row) * 16384 + k0 + kk + scol;
      if (USE_XB) {
        *(uint4*)(As + row * 72 + scol) = *(const uint4*)(xb + ga);
      } else {
        float4 a0 = *(const float4*)(attn + ga);
        float4 a1 = *(const float4*)(attn + ga + 4);
        float4 q0 = *(const float4*)(query + ga);
        float4 q1 = *(const float4*)(query + ga + 4);
        ushort4 h0, h1;
        h0.x = f2h_bits(a0.x + q0.x); h0.y = f2h_bits(a0.y + q0.y);
        h0.z = f2h_bits(a0.z + q0.z); h0.w = f2h_bits(a0.w + q0.w);
        h1.x = f2h_bits(a1.x + q1.x); h1.y = f2h_bits(a1.y + q1.y);
        h1.z = f2h_bits(a1.z + q1.z); h1.w = f2h_bits(a1.w + q1.w);
        *(ushort4*)(As + row * 72 + scol) = h0;
        *(ushort4*)(As + row * 72 + scol + 4) = h1;
      }
      size_t gw = (size_t)(n0 + row) * 16384 + k0 + kk + scol;
      *(uint4*)(Bs + row * 72 + scol) = *(const uint4*)(Wb + gw);
    }
    __syncthreads();
#pragma unroll
    for (int ks = 0; ks < 2; ++ks) {
      const int colb = ks * 32 + q * 8;
      h16x8 af = *(const h16x8*)(As + (16 * w + n) * 72 + colb);
#pragma unroll
      for (int c = 0; c < 4; ++c) {
        h16x8 bf = *(const h16x8*)(Bs + (16 * c + n) * 72 + colb);
        acc[c] = mfma16h(af, bf, acc[c]);
      }
    }
    __syncthreads();
  }
#pragma unroll
  for (int r = 0; r < 4; ++r) {
    int m = m0 + 16 * w + 4 * q + r;
#pragma unroll
    for (int c = 0; c < 4; ++c) {
      int nn = n0 + 16 * c + n;
      part[((size_t)blockIdx.z * 2048 + m) * 256 + nn] = acc[c][r];
    }
  }
}

// ---------------- reduce K-split partials + bias + ReLU ----------------
__global__ __launch_bounds__(256) void relu_kernel(const float* __restrict__ part,
                                                   const float* __restrict__ bias,
                                                   float* __restrict__ out, int KS) {
  int idx = blockIdx.x * 256 + threadIdx.x;
  float s = bias[idx & 255];
  for (int ks = 0; ks < KS; ++ks) s += part[(size_t)ks * 2048 * 256 + idx];
  out[idx] = fmaxf(s, 0.f);
}

extern "C" void kernel_launch(void* const* d_in, const int* in_sizes, int n_in,
                              void* d_out, int out_size, void* d_ws, size_t ws_size,
                              hipStream_t stream) {
  const float* value = (const float*)d_in[0];
  const float* key   = (const float*)d_in[1];
  const float* query = (const float*)d_in[2];
  // d_in[3] = mask, unused by the block
  const float* W_ff  = (const float*)d_in[4];
  const float* b_ff  = (const float*)d_in[5];

  float* out  = (float*)d_out;
  float* attn = out + (size_t)2048 * 256;  // outputs: (out, attention) concatenated

  const int KS = 4;
  const size_t wb_bytes   = (size_t)256 * 16384 * 2;      // 8 MB f16 W
  const size_t part_bytes = (size_t)KS * 2048 * 256 * 4;  // 8 MB fp32 partials
  const size_t xb_bytes   = (size_t)2048 * 64 * 256 * 2;  // 64 MB f16 x
  unsigned short* Wb = (unsigned short*)d_ws;
  float* part = (float*)((char*)d_ws + wb_bytes);
  bool use_xb = ws_size >= wb_bytes + part_bytes + xb_bytes;
  unsigned short* xb =
      use_xb ? (unsigned short*)((char*)d_ws + wb_bytes + part_bytes) : nullptr;

  w2b_kernel<<<4096, 256, 0, stream>>>(W_ff, Wb);
  attn_kernel<<<2048, 256, 0, stream>>>(value, key, query, attn, xb);
  dim3 gb(32, 4, KS);
  if (use_xb)
    ff_kernel<true><<<gb, 256, 0, stream>>>(xb, nullptr, nullptr, Wb, part, 16384 / KS);
  else
    ff_kernel<false><<<gb, 256, 0, stream>>>(nullptr, attn, query, Wb, part, 16384 / KS);
  relu_kernel<<<2048, 256, 0, stream>>>(part, b_ff, out, KS);
}